// Round 3
// baseline (1030.592 us; speedup 1.0000x reference)
//
#include <hip/hip_runtime.h>

#define D_ 1024
#define S_ 2048
#define B_ 32
#define BM 128
#define BN 128
#define BK 32
#define NKT 64  // K tiles: 32 from W/k + 32 from U/q

typedef unsigned short ushort_t;
typedef __attribute__((ext_vector_type(8))) short short8v;   // 8 bf16 = 4 VGPR
typedef __attribute__((ext_vector_type(16))) float f32x16;   // MFMA 32x32 acc
typedef __attribute__((ext_vector_type(4))) unsigned int u32x4;

// async global->LDS, 16B per lane. LDS dest is wave-uniform base + lane*16;
// our per-lane pointers are linear in lane, so this matches exactly.
__device__ __forceinline__ void async_ld16(const ushort_t* g, ushort_t* l) {
  __builtin_amdgcn_global_load_lds(
      (const __attribute__((address_space(1))) void*)g,
      (__attribute__((address_space(3))) void*)l, 16, 0, 0);
}

// ---------------------------------------------------------------------------
// prep: split W,U (f32) into bf16 hi/lo, stored in FRAGMENT ORDER per
// 128x32 tile: granule(m, chunk) = ((wr*2+ks)*2+fm)*64 + lhi*32 + l31
//   where m = wr*64+fm*32+l31 (row), chunk = ks*2+lhi (8-elem k-group).
// => gemm's A-stage is a linear 8KB copy (global_load_lds) and every MFMA
//    fragment ds_read_b128 is 64 lanes x 16B contiguous: zero bank conflicts.
// ---------------------------------------------------------------------------
__global__ void prep_kernel(const float* __restrict__ W, const float* __restrict__ U,
                            ushort_t* __restrict__ whi, ushort_t* __restrict__ wlo,
                            ushort_t* __restrict__ uhi, ushort_t* __restrict__ ulo) {
  int t = blockIdx.x * blockDim.x + threadIdx.x;  // [0, 131072) granules
  const float* src = blockIdx.y ? U : W;
  ushort_t* dhi = blockIdx.y ? uhi : whi;
  ushort_t* dlo = blockIdx.y ? ulo : wlo;

  int tile = t >> 9;        // [0,256) = mt*32 + kt
  int g    = t & 511;       // granule within tile
  int top  = g >> 6, lane = g & 63;
  int wr = top >> 2, ks = (top >> 1) & 1, fm = top & 1;
  int l31 = lane & 31, lhi = lane >> 5;
  int m     = wr * 64 + fm * 32 + l31;
  int chunk = ks * 2 + lhi;
  int mt = tile >> 5, kt = tile & 31;
  int d = mt * 128 + m;
  int e = kt * 32 + chunk * 8;

  const float* p = src + (size_t)d * D_ + e;
  ushort_t hi[8], lo[8];
#pragma unroll
  for (int j = 0; j < 8; ++j) {
    float x = p[j];
    unsigned u = __float_as_uint(x);
    unsigned hb = u & 0xFFFF0000u;          // hi = truncate-to-bf16 (exact residual)
    float lf = x - __uint_as_float(hb);     // exact in f32
    hi[j] = (ushort_t)(hb >> 16);
    lo[j] = (ushort_t)((__float_as_uint(lf) + 0x8000u) >> 16);  // round lo
  }
  u32x4 hv, lv;
#pragma unroll
  for (int w = 0; w < 4; ++w) {
    hv[w] = (unsigned)hi[2 * w] | ((unsigned)hi[2 * w + 1] << 16);
    lv[w] = (unsigned)lo[2 * w] | ((unsigned)lo[2 * w + 1] << 16);
  }
  *(u32x4*)(dhi + (size_t)t * 8) = hv;   // linear, coalesced
  *(u32x4*)(dlo + (size_t)t * 8) = lv;
}

// ---------------------------------------------------------------------------
// gemm v3: 2-phase prefetch pipeline (double-buffered LDS, one barrier/kt).
// Per iteration: issue next A (global_load_lds) + next B (global->reg) loads,
// compute current tile (ds_read + 24 MFMA), then split+write next B, barrier.
// Global latency hides under the MFMA/ds_read phase.
// ---------------------------------------------------------------------------
__global__ void __launch_bounds__(256, 2)
gemm_kernel(const float* __restrict__ kten, const float* __restrict__ qten,
            const float* __restrict__ v,
            const ushort_t* __restrict__ whi, const ushort_t* __restrict__ wlo,
            const ushort_t* __restrict__ uhi, const ushort_t* __restrict__ ulo,
            float* __restrict__ partials) {
  __shared__ __align__(16) ushort_t Ah[2][BM * BK];
  __shared__ __align__(16) ushort_t Al[2][BM * BK];
  __shared__ __align__(16) ushort_t Bh[2][BN * BK];
  __shared__ __align__(16) ushort_t Bl[2][BN * BK];
  __shared__ float vbuf[BM];
  __shared__ float red[2][BN];

  const int tid  = threadIdx.x;
  const int lane = tid & 63;
  const int wid  = tid >> 6;
  const int wr   = wid >> 1, wc = wid & 1;

  // Block decode: the 8 d-sibling blocks of a (b, s-tile) group share bid&7
  // -> same XCD under round-robin dispatch -> k/q tiles served from L2.
  int bid  = blockIdx.x;
  int g    = ((bid >> 6) << 3) | (bid & 7);  // [0,512)
  int dblk = (bid >> 3) & 7;
  int st   = g & 15;
  int b    = g >> 4;
  int s0   = st * BN;

  if (tid < BM) vbuf[tid] = v[(size_t)b * D_ + dblk * BM + tid];

  f32x16 acc[2][2];
#pragma unroll
  for (int i = 0; i < 2; ++i)
#pragma unroll
    for (int j = 0; j < 2; ++j)
#pragma unroll
      for (int r = 0; r < 16; ++r) acc[i][j][r] = 0.0f;

  const int nB = tid & 127;  // B-stage column within s-tile
  const int kq = tid >> 7;   // 0/1: which 16 k-rows this thread loads

  // --- staging helpers -----------------------------------------------------
  auto issueA = [&](int kt, int buf) {
    const int half = kt >> 5, ktt = kt & 31;
    const size_t toff = (size_t)(dblk * 32 + ktt) * 4096;
    const ushort_t* ah = (half ? uhi : whi) + toff;
    const ushort_t* al = (half ? ulo : wlo) + toff;
    async_ld16(ah + (size_t)tid * 8,         &Ah[buf][(size_t)tid * 8]);
    async_ld16(ah + (size_t)(tid + 256) * 8, &Ah[buf][(size_t)(tid + 256) * 8]);
    async_ld16(al + (size_t)tid * 8,         &Al[buf][(size_t)tid * 8]);
    async_ld16(al + (size_t)(tid + 256) * 8, &Al[buf][(size_t)(tid + 256) * 8]);
  };
  auto loadB = [&](int kt, float* xv) {
    const int half = kt >> 5, ktt = kt & 31;
    const float* xb = (half ? qten : kten) + (size_t)b * (D_ * S_) + (size_t)(ktt * 32) * S_ + s0;
    const float* col = xb + nB + (size_t)(kq * 16) * S_;
#pragma unroll
    for (int j = 0; j < 16; ++j) xv[j] = col[(size_t)j * S_];
  };
  auto splitB = [&](const float* xv, int buf) {
    ushort_t hi[16], lo[16];
#pragma unroll
    for (int j = 0; j < 16; ++j) {
      unsigned u = __float_as_uint(xv[j]);
      unsigned hb = u & 0xFFFF0000u;
      float lf = xv[j] - __uint_as_float(hb);
      hi[j] = (ushort_t)(hb >> 16);
      lo[j] = (ushort_t)((__float_as_uint(lf) + 0x8000u) >> 16);
    }
#pragma unroll
    for (int jj = 0; jj < 2; ++jj) {
      // granule = ((wc_n*2 + ks)*2 + fn)*64 + jj*32 + l31, ks=kq, lhi=jj
      int gnl = ((((nB >> 6) * 2 + kq) * 2 + ((nB >> 5) & 1)) << 6) + (jj << 5) + (nB & 31);
      u32x4 hv, lv;
#pragma unroll
      for (int w = 0; w < 4; ++w) {
        hv[w] = (unsigned)hi[jj * 8 + 2 * w] | ((unsigned)hi[jj * 8 + 2 * w + 1] << 16);
        lv[w] = (unsigned)lo[jj * 8 + 2 * w] | ((unsigned)lo[jj * 8 + 2 * w + 1] << 16);
      }
      *(u32x4*)&Bh[buf][(size_t)gnl * 8] = hv;
      *(u32x4*)&Bl[buf][(size_t)gnl * 8] = lv;
    }
  };

  // --- prologue: stage kt=0 into buf 0 --------------------------------------
  float xv[16];
  issueA(0, 0);
  loadB(0, xv);
  splitB(xv, 0);
  __syncthreads();  // drains vmcnt (async A) + lgkm (ds_write)

  int cur = 0;
  for (int kt = 0; kt < NKT; ++kt) {
    const int nxt = cur ^ 1;
    const int ktn = (kt + 1 < NKT) ? kt + 1 : kt;  // clamped: last iter redundant

    // ---- issue next-tile loads (latency hides under compute below) ----
    issueA(ktn, nxt);
    loadB(ktn, xv);

    // ---- compute current tile: 2 k-steps x 2x2 frags x 3 passes = 24 MFMA --
#pragma unroll
    for (int ks = 0; ks < 2; ++ks) {
      short8v ahf[2], alf[2], bhf[2], blf[2];
#pragma unroll
      for (int fm = 0; fm < 2; ++fm) {
        int gA = (((wr * 2 + ks) * 2 + fm) << 6) + lane;  // contiguous per wave
        ahf[fm] = *(const short8v*)&Ah[cur][(size_t)gA * 8];
        alf[fm] = *(const short8v*)&Al[cur][(size_t)gA * 8];
      }
#pragma unroll
      for (int fn = 0; fn < 2; ++fn) {
        int gB = (((wc * 2 + ks) * 2 + fn) << 6) + lane;
        bhf[fn] = *(const short8v*)&Bh[cur][(size_t)gB * 8];
        blf[fn] = *(const short8v*)&Bl[cur][(size_t)gB * 8];
      }
#pragma unroll
      for (int fm = 0; fm < 2; ++fm)
#pragma unroll
        for (int fn = 0; fn < 2; ++fn) {
          acc[fm][fn] = __builtin_amdgcn_mfma_f32_32x32x16_bf16(ahf[fm], bhf[fn], acc[fm][fn], 0, 0, 0);
          acc[fm][fn] = __builtin_amdgcn_mfma_f32_32x32x16_bf16(ahf[fm], blf[fn], acc[fm][fn], 0, 0, 0);
          acc[fm][fn] = __builtin_amdgcn_mfma_f32_32x32x16_bf16(alf[fm], bhf[fn], acc[fm][fn], 0, 0, 0);
          // lo*lo dropped: ~2^-18 relative, negligible
        }
    }

    // ---- split + write next B tile (waits vmcnt for xv), one barrier/kt ----
    splitB(xv, nxt);
    __syncthreads();
    cur = nxt;
  }

  // ---- epilogue: tanh, weight by v[d], reduce columns over the 128 d-rows --
  float psum[2] = {0.f, 0.f};
#pragma unroll
  for (int fm = 0; fm < 2; ++fm)
#pragma unroll
    for (int fn = 0; fn < 2; ++fn)
#pragma unroll
      for (int r = 0; r < 16; ++r) {
        // C/D layout: col = lane&31, row = (r&3)+8*(r>>2)+4*(lane>>5)
        int row = wr * 64 + fm * 32 + (r & 3) + 8 * (r >> 2) + 4 * (lane >> 5);
        float x  = acc[fm][fn][r];
        float th = 1.0f - 2.0f / (__expf(2.0f * x) + 1.0f);  // tanh(x)
        psum[fn] += vbuf[row] * th;
      }
#pragma unroll
  for (int fn = 0; fn < 2; ++fn) psum[fn] += __shfl_xor(psum[fn], 32);
  if (lane < 32) {
    red[wr][wc * 64 + lane]      = psum[0];
    red[wr][wc * 64 + 32 + lane] = psum[1];
  }
  __syncthreads();
  if (tid < BN) {
    float val = red[0][tid] + red[1][tid];
    partials[(size_t)(dblk * B_ + b) * S_ + s0 + tid] = val;
  }
}

// ---------------------------------------------------------------------------
// softmax over S per batch; sums the 8 d-block partials first. Deterministic.
// ---------------------------------------------------------------------------
__global__ void softmax_kernel(const float* __restrict__ partials, float* __restrict__ out) {
  __shared__ float logit[S_];
  __shared__ float wred[2][4];
  int b = blockIdx.x, tid = threadIdx.x;
  int lane = tid & 63, wid = tid >> 6;
  float lmax = -1e30f;
  for (int i = tid; i < S_; i += 256) {
    float acc = 0.f;
#pragma unroll
    for (int d = 0; d < 8; ++d) acc += partials[(size_t)(d * B_ + b) * S_ + i];
    logit[i] = acc;
    lmax = fmaxf(lmax, acc);
  }
#pragma unroll
  for (int o = 32; o; o >>= 1) lmax = fmaxf(lmax, __shfl_xor(lmax, o));
  if (lane == 0) wred[0][wid] = lmax;
  __syncthreads();
  float m = fmaxf(fmaxf(wred[0][0], wred[0][1]), fmaxf(wred[0][2], wred[0][3]));
  float lsum = 0.f;
  for (int i = tid; i < S_; i += 256) {
    float ex = __expf(logit[i] - m);
    logit[i] = ex;
    lsum += ex;
  }
#pragma unroll
  for (int o = 32; o; o >>= 1) lsum += __shfl_xor(lsum, o);
  if (lane == 0) wred[1][wid] = lsum;
  __syncthreads();
  float tot = wred[1][0] + wred[1][1] + wred[1][2] + wred[1][3];
  float inv = 1.0f / tot;
  for (int i = tid; i < S_; i += 256) out[(size_t)b * S_ + i] = logit[i] * inv;
}

extern "C" void kernel_launch(void* const* d_in, const int* in_sizes, int n_in,
                              void* d_out, int out_size, void* d_ws, size_t ws_size,
                              hipStream_t stream) {
  const float* q = (const float*)d_in[0];
  const float* k = (const float*)d_in[1];
  const float* v = (const float*)d_in[2];
  const float* W = (const float*)d_in[3];
  const float* U = (const float*)d_in[4];

  // ws layout: 4x bf16[1024*1024] (8 MB) + partials f32[8][32][2048] (2 MB)
  ushort_t* whi = (ushort_t*)d_ws;
  ushort_t* wlo = whi + (size_t)D_ * D_;
  ushort_t* uhi = wlo + (size_t)D_ * D_;
  ushort_t* ulo = uhi + (size_t)D_ * D_;
  float* partials = (float*)(ulo + (size_t)D_ * D_);

  prep_kernel<<<dim3(512, 2), 256, 0, stream>>>(W, U, whi, wlo, uhi, ulo);
  gemm_kernel<<<dim3(4096), 256, 0, stream>>>(k, q, v, whi, wlo, uhi, ulo, partials);
  softmax_kernel<<<dim3(B_), 256, 0, stream>>>(partials, (float*)d_out);
}

// Round 4
// 873.061 us; speedup vs baseline: 1.1804x; 1.1804x over previous
//
#include <hip/hip_runtime.h>

#define D_ 1024
#define S_ 2048
#define B_ 32
#define BM 128
#define BN 128
#define BK 32
#define NKT 64  // K tiles: 32 from W/k + 32 from U/q
#define ASCALE 4096.0f      // exact pow2 pre-scale on W,U: keeps f16 lo-plane normal
#define INV_ASCALE (1.0f / 4096.0f)

typedef __attribute__((ext_vector_type(8))) _Float16 f16x8;  // 4 VGPR MFMA operand
typedef __attribute__((ext_vector_type(16))) float f32x16;   // MFMA 32x32 acc

// async global->LDS, 16B per lane. LDS dest is wave-uniform base + lane*16;
// our per-lane pointers are linear in lane, so this matches exactly.
__device__ __forceinline__ void async_ld16(const void* g, void* l) {
  __builtin_amdgcn_global_load_lds(
      (const __attribute__((address_space(1))) void*)g,
      (__attribute__((address_space(3))) void*)l, 16, 0, 0);
}

// ---------------------------------------------------------------------------
// prep: scale W,U by 4096 (exact) and split into f16 hi/lo, stored in
// FRAGMENT ORDER per 128x32 tile (same layout as R2, verified):
//   granule(m, chunk) = ((wr*2+ks)*2+fm)*64 + lhi*32 + l31
// => gemm A-stage is a linear 8KB copy (global_load_lds); every fragment
//    ds_read_b128 is 64 lanes x 16B contiguous: zero bank conflicts.
// hi = f16(4096*x) (11-bit), lo = f16(4096*x - hi): A rel err ~2^-22.
// ---------------------------------------------------------------------------
__global__ void prep_kernel(const float* __restrict__ W, const float* __restrict__ U,
                            _Float16* __restrict__ whi, _Float16* __restrict__ wlo,
                            _Float16* __restrict__ uhi, _Float16* __restrict__ ulo) {
  int t = blockIdx.x * blockDim.x + threadIdx.x;  // [0, 131072) granules
  const float* src = blockIdx.y ? U : W;
  _Float16* dhi = blockIdx.y ? uhi : whi;
  _Float16* dlo = blockIdx.y ? ulo : wlo;

  int tile = t >> 9;        // [0,256) = mt*32 + kt
  int g    = t & 511;       // granule within tile
  int top  = g >> 6, lane = g & 63;
  int wr = top >> 2, ks = (top >> 1) & 1, fm = top & 1;
  int l31 = lane & 31, lhi = lane >> 5;
  int m     = wr * 64 + fm * 32 + l31;
  int chunk = ks * 2 + lhi;
  int mt = tile >> 5, kt = tile & 31;
  int d = mt * 128 + m;
  int e = kt * 32 + chunk * 8;

  const float* p = src + (size_t)d * D_ + e;
  f16x8 hv, lv;
#pragma unroll
  for (int j = 0; j < 8; ++j) {
    float xs = p[j] * ASCALE;
    _Float16 h = (_Float16)xs;           // RN, 11-bit
    hv[j] = h;
    lv[j] = (_Float16)(xs - (float)h);   // residual, normal-range after scaling
  }
  *(f16x8*)(dhi + (size_t)t * 8) = hv;   // linear, coalesced
  *(f16x8*)(dlo + (size_t)t * 8) = lv;
}

// ---------------------------------------------------------------------------
// gemm v4: R2's proven single-buffered 2-barrier structure, numeric scheme
// switched to 2-pass f16: fac*4096 = (Ahi + Alo) @ f16(B), 16 MFMA/kt/wave.
// A staged via global_load_lds (linear, fragment-order); B: 16 coalesced
// strided f32 loads -> f16 cvt -> 2 ds_write_b128 in fragment order.
// ---------------------------------------------------------------------------
__global__ void __launch_bounds__(256, 5)
gemm_kernel(const float* __restrict__ kten, const float* __restrict__ qten,
            const float* __restrict__ v,
            const _Float16* __restrict__ whi, const _Float16* __restrict__ wlo,
            const _Float16* __restrict__ uhi, const _Float16* __restrict__ ulo,
            float* __restrict__ partials) {
  __shared__ __align__(16) _Float16 Ah[BM * BK];   // 8 KB
  __shared__ __align__(16) _Float16 Al[BM * BK];   // 8 KB
  __shared__ __align__(16) _Float16 Bh[BN * BK];   // 8 KB
  __shared__ float vbuf[BM];
  __shared__ float red[2][BN];

  const int tid  = threadIdx.x;
  const int lane = tid & 63;
  const int wid  = tid >> 6;
  const int wr   = wid >> 1, wc = wid & 1;

  // Block decode: the 8 d-sibling blocks of a (b, s-tile) group share bid&7
  // -> same XCD under round-robin dispatch -> k/q tiles served from L2.
  int bid  = blockIdx.x;
  int g    = ((bid >> 6) << 3) | (bid & 7);  // [0,512)
  int dblk = (bid >> 3) & 7;
  int st   = g & 15;
  int b    = g >> 4;
  int s0   = st * BN;

  if (tid < BM) vbuf[tid] = v[(size_t)b * D_ + dblk * BM + tid];

  f32x16 acc[2][2];
#pragma unroll
  for (int i = 0; i < 2; ++i)
#pragma unroll
    for (int j = 0; j < 2; ++j)
#pragma unroll
      for (int r = 0; r < 16; ++r) acc[i][j][r] = 0.0f;

  const int nB = tid & 127;  // B-stage column within s-tile
  const int kq = tid >> 7;   // 0/1: which 16 k-rows this thread loads

  for (int kt = 0; kt < NKT; ++kt) {
    const int half = kt >> 5;  // 0: W with k, 1: U with q
    const int ktt  = kt & 31;
    const size_t toff = (size_t)(dblk * 32 + ktt) * 4096;
    const _Float16* ah = (half ? uhi : whi) + toff;
    const _Float16* al = (half ? ulo : wlo) + toff;
    const float* xb = (half ? qten : kten) + (size_t)b * (D_ * S_) + (size_t)(ktt * 32) * S_ + s0;

    __syncthreads();  // previous compute done reading LDS

    // ---- stage A: async linear copy of fragment-ordered 8KB hi/lo tiles ----
    async_ld16(ah + (size_t)tid * 8,         Ah + (size_t)tid * 8);
    async_ld16(ah + (size_t)(tid + 256) * 8, Ah + (size_t)(tid + 256) * 8);
    async_ld16(al + (size_t)tid * 8,         Al + (size_t)tid * 8);
    async_ld16(al + (size_t)(tid + 256) * 8, Al + (size_t)(tid + 256) * 8);

    // ---- stage B: coalesced strided f32 loads -> f16 -> fragment-order LDS --
    {
      float xv[16];
      const float* col = xb + nB + (size_t)(kq * 16) * S_;
#pragma unroll
      for (int j = 0; j < 16; ++j) xv[j] = col[(size_t)j * S_];
#pragma unroll
      for (int jj = 0; jj < 2; ++jj) {
        f16x8 hv;
#pragma unroll
        for (int w = 0; w < 8; ++w) hv[w] = (_Float16)xv[jj * 8 + w];
        // granule = ((wc_n*2 + ks)*2 + fn)*64 + jj*32 + l31, ks=kq
        int gnl = ((((nB >> 6) * 2 + kq) * 2 + ((nB >> 5) & 1)) << 6) + (jj << 5) + (nB & 31);
        *(f16x8*)&Bh[(size_t)gnl * 8] = hv;
      }
    }

    __syncthreads();  // staged tiles visible (sync drains vmcnt + lgkm)

    // ---- compute: 2 k-steps x 2x2 frags x 2 passes = 16 MFMA ----
#pragma unroll
    for (int ks = 0; ks < 2; ++ks) {
      f16x8 ahf[2], alf[2], bhf[2];
#pragma unroll
      for (int fm = 0; fm < 2; ++fm) {
        int gA = (((wr * 2 + ks) * 2 + fm) << 6) + lane;  // contiguous per wave
        ahf[fm] = *(const f16x8*)&Ah[(size_t)gA * 8];
        alf[fm] = *(const f16x8*)&Al[(size_t)gA * 8];
      }
#pragma unroll
      for (int fn = 0; fn < 2; ++fn) {
        int gB = (((wc * 2 + ks) * 2 + fn) << 6) + lane;
        bhf[fn] = *(const f16x8*)&Bh[(size_t)gB * 8];
      }
#pragma unroll
      for (int fm = 0; fm < 2; ++fm)
#pragma unroll
        for (int fn = 0; fn < 2; ++fn) {
          acc[fm][fn] = __builtin_amdgcn_mfma_f32_32x32x16_f16(ahf[fm], bhf[fn], acc[fm][fn], 0, 0, 0);
          acc[fm][fn] = __builtin_amdgcn_mfma_f32_32x32x16_f16(alf[fm], bhf[fn], acc[fm][fn], 0, 0, 0);
        }
    }
  }

  // ---- epilogue: unscale, tanh, weight by v[d], column-reduce 128 d-rows ----
  float psum[2] = {0.f, 0.f};
#pragma unroll
  for (int fm = 0; fm < 2; ++fm)
#pragma unroll
    for (int fn = 0; fn < 2; ++fn)
#pragma unroll
      for (int r = 0; r < 16; ++r) {
        // C/D layout: col = lane&31, row = (r&3)+8*(r>>2)+4*(lane>>5)
        int row = wr * 64 + fm * 32 + (r & 3) + 8 * (r >> 2) + 4 * (lane >> 5);
        float x  = acc[fm][fn][r] * INV_ASCALE;
        float th = 1.0f - 2.0f / (__expf(2.0f * x) + 1.0f);  // tanh(x)
        psum[fn] += vbuf[row] * th;
      }
#pragma unroll
  for (int fn = 0; fn < 2; ++fn) psum[fn] += __shfl_xor(psum[fn], 32);
  if (lane < 32) {
    red[wr][wc * 64 + lane]      = psum[0];
    red[wr][wc * 64 + 32 + lane] = psum[1];
  }
  __syncthreads();
  if (tid < BN) {
    float val = red[0][tid] + red[1][tid];
    partials[(size_t)(dblk * B_ + b) * S_ + s0 + tid] = val;
  }
}

// ---------------------------------------------------------------------------
// softmax over S per batch; sums the 8 d-block partials first. Deterministic.
// ---------------------------------------------------------------------------
__global__ void softmax_kernel(const float* __restrict__ partials, float* __restrict__ out) {
  __shared__ float logit[S_];
  __shared__ float wred[2][4];
  int b = blockIdx.x, tid = threadIdx.x;
  int lane = tid & 63, wid = tid >> 6;
  float lmax = -1e30f;
  for (int i = tid; i < S_; i += 256) {
    float acc = 0.f;
#pragma unroll
    for (int d = 0; d < 8; ++d) acc += partials[(size_t)(d * B_ + b) * S_ + i];
    logit[i] = acc;
    lmax = fmaxf(lmax, acc);
  }
#pragma unroll
  for (int o = 32; o; o >>= 1) lmax = fmaxf(lmax, __shfl_xor(lmax, o));
  if (lane == 0) wred[0][wid] = lmax;
  __syncthreads();
  float m = fmaxf(fmaxf(wred[0][0], wred[0][1]), fmaxf(wred[0][2], wred[0][3]));
  float lsum = 0.f;
  for (int i = tid; i < S_; i += 256) {
    float ex = __expf(logit[i] - m);
    logit[i] = ex;
    lsum += ex;
  }
#pragma unroll
  for (int o = 32; o; o >>= 1) lsum += __shfl_xor(lsum, o);
  if (lane == 0) wred[1][wid] = lsum;
  __syncthreads();
  float tot = wred[1][0] + wred[1][1] + wred[1][2] + wred[1][3];
  float inv = 1.0f / tot;
  for (int i = tid; i < S_; i += 256) out[(size_t)b * S_ + i] = logit[i] * inv;
}

extern "C" void kernel_launch(void* const* d_in, const int* in_sizes, int n_in,
                              void* d_out, int out_size, void* d_ws, size_t ws_size,
                              hipStream_t stream) {
  const float* q = (const float*)d_in[0];
  const float* k = (const float*)d_in[1];
  const float* v = (const float*)d_in[2];
  const float* W = (const float*)d_in[3];
  const float* U = (const float*)d_in[4];

  // ws layout: 4x f16[1024*1024] (8 MB) + partials f32[8][32][2048] (2 MB)
  _Float16* whi = (_Float16*)d_ws;
  _Float16* wlo = whi + (size_t)D_ * D_;
  _Float16* uhi = wlo + (size_t)D_ * D_;
  _Float16* ulo = uhi + (size_t)D_ * D_;
  float* partials = (float*)(ulo + (size_t)D_ * D_);

  prep_kernel<<<dim3(512, 2), 256, 0, stream>>>(W, U, whi, wlo, uhi, ulo);
  gemm_kernel<<<dim3(4096), 256, 0, stream>>>(k, q, v, whi, wlo, uhi, ulo, partials);
  softmax_kernel<<<dim3(B_), 256, 0, stream>>>(partials, (float*)d_out);
}

// Round 5
// 525.510 us; speedup vs baseline: 1.9611x; 1.6614x over previous
//
#include <hip/hip_runtime.h>

#define D_ 1024
#define S_ 2048
#define B_ 32
#define BM 128
#define BN 128
#define BK 64
#define NKT 32  // K tiles: 16 from W/k + 16 from U/q (BK=64)

typedef __attribute__((ext_vector_type(8))) _Float16 f16x8;  // 4 VGPR MFMA operand
typedef __attribute__((ext_vector_type(16))) float f32x16;   // MFMA 32x32 acc

// async global->LDS, 16B per lane. LDS dest is wave-uniform base + lane*16;
// our per-lane pointers are linear in lane, so this matches exactly.
__device__ __forceinline__ void async_ld16(const void* g, void* l) {
  __builtin_amdgcn_global_load_lds(
      (const __attribute__((address_space(1))) void*)g,
      (__attribute__((address_space(3))) void*)l, 16, 0, 0);
}

// ---------------------------------------------------------------------------
// prep: round W,U to single f16 plane, stored in FRAGMENT ORDER per 128x64
// tile (1024 granules of 8 f16):
//   granule = ((ks*4 + wr*2 + fm) << 6) | (lhi << 5) | l31
//   row     = wr*64 + fm*32 + l31      (d within tile)
//   chunk   = ks*2 + lhi               (8-elem k-group within 64)
// => gemm A-stage is a linear 16KB copy (global_load_lds); every fragment
//    ds_read_b128 is 64 lanes x 16B contiguous: zero bank conflicts.
// 1-pass numerics: A rel err 2^-11 (RN), B rel err 2^-11 -> absmax ~6e-3.
// ---------------------------------------------------------------------------
__global__ void prep_kernel(const float* __restrict__ W, const float* __restrict__ U,
                            _Float16* __restrict__ wf, _Float16* __restrict__ uf) {
  int t = blockIdx.x * blockDim.x + threadIdx.x;  // [0, 131072) granules
  const float* src = blockIdx.y ? U : W;
  _Float16* dst = blockIdx.y ? uf : wf;

  int tile = t >> 10;       // [0,128) = mt*16 + kt
  int g    = t & 1023;      // granule within tile
  int top  = g >> 6;        // [0,16)
  int ks = top >> 2, wr = (top >> 1) & 1, fm = top & 1;
  int lhi = (g >> 5) & 1, l31 = g & 31;
  int row   = wr * 64 + fm * 32 + l31;
  int chunk = ks * 2 + lhi;
  int mt = tile >> 4, kt = tile & 15;
  int d = mt * 128 + row;
  int e = kt * 64 + chunk * 8;

  const float* p = src + (size_t)d * D_ + e;
  f16x8 hv;
#pragma unroll
  for (int j = 0; j < 8; ++j) hv[j] = (_Float16)p[j];  // RN
  *(f16x8*)(dst + (size_t)t * 8) = hv;                 // linear, coalesced
}

// ---------------------------------------------------------------------------
// gemm v5: single-buffered 2-barrier structure, BK=64 (32 iterations),
// 1-pass f16: fac = f16(A) @ f16(B), 16 MFMA/kt/wave.
// A staged via global_load_lds (linear, fragment-order, 16KB);
// B: 32 coalesced strided f32 loads -> f16 cvt -> 4 ds_write_b128 (frag order).
// ---------------------------------------------------------------------------
__global__ void __launch_bounds__(256, 4)
gemm_kernel(const float* __restrict__ kten, const float* __restrict__ qten,
            const float* __restrict__ v,
            const _Float16* __restrict__ wf, const _Float16* __restrict__ uf,
            float* __restrict__ partials) {
  __shared__ __align__(16) _Float16 Af[BM * BK];   // 16 KB
  __shared__ __align__(16) _Float16 Bf[BN * BK];   // 16 KB
  __shared__ float vbuf[BM];
  __shared__ float red[2][BN];

  const int tid  = threadIdx.x;
  const int lane = tid & 63;
  const int wid  = tid >> 6;
  const int wr   = wid >> 1, wc = wid & 1;

  // Block decode: the 8 d-sibling blocks of a (b, s-tile) group share bid&7
  // -> same XCD under round-robin dispatch -> k/q tiles served from L2.
  int bid  = blockIdx.x;
  int g    = ((bid >> 6) << 3) | (bid & 7);  // [0,512)
  int dblk = (bid >> 3) & 7;
  int st   = g & 15;
  int b    = g >> 4;
  int s0   = st * BN;

  if (tid < BM) vbuf[tid] = v[(size_t)b * D_ + dblk * BM + tid];

  f32x16 acc[2][2];
#pragma unroll
  for (int i = 0; i < 2; ++i)
#pragma unroll
    for (int j = 0; j < 2; ++j)
#pragma unroll
      for (int r = 0; r < 16; ++r) acc[i][j][r] = 0.0f;

  const int nB = tid & 127;  // B-stage column within s-tile
  const int kq = tid >> 7;   // 0/1: which 32 of the 64 k-rows this thread loads

  for (int kt = 0; kt < NKT; ++kt) {
    const int half = kt >> 4;  // 0: W with k, 1: U with q
    const int ktt  = kt & 15;
    const _Float16* at = (half ? uf : wf) + (size_t)(dblk * 16 + ktt) * 8192;
    const float* xb = (half ? qten : kten) + (size_t)b * (D_ * S_) + (size_t)(ktt * 64) * S_ + s0;

    __syncthreads();  // previous compute done reading LDS

    // ---- stage A: async linear copy of fragment-ordered 16KB tile ----
#pragma unroll
    for (int i = 0; i < 4; ++i)
      async_ld16(at + (size_t)(tid + i * 256) * 8, Af + (size_t)(tid + i * 256) * 8);

    // ---- stage B: coalesced strided f32 loads -> f16 -> fragment-order LDS,
    //      two half-batches of 16 rows to bound VGPR use ----
#pragma unroll
    for (int hb = 0; hb < 2; ++hb) {
      float xv[16];
      const float* col = xb + nB + (size_t)(kq * 32 + hb * 16) * S_;
#pragma unroll
      for (int j = 0; j < 16; ++j) xv[j] = col[(size_t)j * S_];
#pragma unroll
      for (int jj = 0; jj < 2; ++jj) {
        f16x8 hv;
#pragma unroll
        for (int w = 0; w < 8; ++w) hv[w] = (_Float16)xv[jj * 8 + w];
        int c   = kq * 4 + hb * 2 + jj;          // chunk in [0,8)
        int cks = c >> 1, clh = c & 1;
        int gnl = (((cks * 4 + (nB >> 6) * 2 + ((nB >> 5) & 1)) << 6) | (clh << 5) | (nB & 31));
        *(f16x8*)&Bf[(size_t)gnl * 8] = hv;
      }
    }

    __syncthreads();  // staged tile visible (drains vmcnt + lgkm)

    // ---- compute: 4 k-steps x 2x2 frags = 16 MFMA / wave ----
#pragma unroll
    for (int ks = 0; ks < 4; ++ks) {
      f16x8 af[2], bf[2];
#pragma unroll
      for (int fm = 0; fm < 2; ++fm) {
        int gA = ((ks * 4 + wr * 2 + fm) << 6) + lane;  // contiguous per wave
        af[fm] = *(const f16x8*)&Af[(size_t)gA * 8];
      }
#pragma unroll
      for (int fn = 0; fn < 2; ++fn) {
        int gB = ((ks * 4 + wc * 2 + fn) << 6) + lane;
        bf[fn] = *(const f16x8*)&Bf[(size_t)gB * 8];
      }
#pragma unroll
      for (int fm = 0; fm < 2; ++fm)
#pragma unroll
        for (int fn = 0; fn < 2; ++fn)
          acc[fm][fn] = __builtin_amdgcn_mfma_f32_32x32x16_f16(af[fm], bf[fn], acc[fm][fn], 0, 0, 0);
    }
  }

  // ---- epilogue: tanh, weight by v[d], column-reduce the 128 d-rows ----
  float psum[2] = {0.f, 0.f};
#pragma unroll
  for (int fm = 0; fm < 2; ++fm)
#pragma unroll
    for (int fn = 0; fn < 2; ++fn)
#pragma unroll
      for (int r = 0; r < 16; ++r) {
        // C/D layout: col = lane&31, row = (r&3)+8*(r>>2)+4*(lane>>5)
        int row = wr * 64 + fm * 32 + (r & 3) + 8 * (r >> 2) + 4 * (lane >> 5);
        float x  = acc[fm][fn][r];
        float th = 1.0f - 2.0f / (__expf(2.0f * x) + 1.0f);  // tanh(x)
        psum[fn] += vbuf[row] * th;
      }
#pragma unroll
  for (int fn = 0; fn < 2; ++fn) psum[fn] += __shfl_xor(psum[fn], 32);
  if (lane < 32) {
    red[wr][wc * 64 + lane]      = psum[0];
    red[wr][wc * 64 + 32 + lane] = psum[1];
  }
  __syncthreads();
  if (tid < BN) {
    float val = red[0][tid] + red[1][tid];
    partials[(size_t)(dblk * B_ + b) * S_ + s0 + tid] = val;
  }
}

// ---------------------------------------------------------------------------
// softmax over S per batch; sums the 8 d-block partials first. Deterministic.
// ---------------------------------------------------------------------------
__global__ void softmax_kernel(const float* __restrict__ partials, float* __restrict__ out) {
  __shared__ float logit[S_];
  __shared__ float wred[2][4];
  int b = blockIdx.x, tid = threadIdx.x;
  int lane = tid & 63, wid = tid >> 6;
  float lmax = -1e30f;
  for (int i = tid; i < S_; i += 256) {
    float acc = 0.f;
#pragma unroll
    for (int d = 0; d < 8; ++d) acc += partials[(size_t)(d * B_ + b) * S_ + i];
    logit[i] = acc;
    lmax = fmaxf(lmax, acc);
  }
#pragma unroll
  for (int o = 32; o; o >>= 1) lmax = fmaxf(lmax, __shfl_xor(lmax, o));
  if (lane == 0) wred[0][wid] = lmax;
  __syncthreads();
  float m = fmaxf(fmaxf(wred[0][0], wred[0][1]), fmaxf(wred[0][2], wred[0][3]));
  float lsum = 0.f;
  for (int i = tid; i < S_; i += 256) {
    float ex = __expf(logit[i] - m);
    logit[i] = ex;
    lsum += ex;
  }
#pragma unroll
  for (int o = 32; o; o >>= 1) lsum += __shfl_xor(lsum, o);
  if (lane == 0) wred[1][wid] = lsum;
  __syncthreads();
  float tot = wred[1][0] + wred[1][1] + wred[1][2] + wred[1][3];
  float inv = 1.0f / tot;
  for (int i = tid; i < S_; i += 256) out[(size_t)b * S_ + i] = logit[i] * inv;
}

extern "C" void kernel_launch(void* const* d_in, const int* in_sizes, int n_in,
                              void* d_out, int out_size, void* d_ws, size_t ws_size,
                              hipStream_t stream) {
  const float* q = (const float*)d_in[0];
  const float* k = (const float*)d_in[1];
  const float* v = (const float*)d_in[2];
  const float* W = (const float*)d_in[3];
  const float* U = (const float*)d_in[4];

  // ws layout: 2x f16[1024*1024] (4 MB) + partials f32[8][32][2048] (2 MB)
  _Float16* wf = (_Float16*)d_ws;
  _Float16* uf = wf + (size_t)D_ * D_;
  float* partials = (float*)(uf + (size_t)D_ * D_);

  prep_kernel<<<dim3(512, 2), 256, 0, stream>>>(W, U, wf, uf);
  gemm_kernel<<<dim3(4096), 256, 0, stream>>>(k, q, v, wf, uf, partials);
  softmax_kernel<<<dim3(B_), 256, 0, stream>>>(partials, (float*)d_out);
}

// Round 7
// 490.685 us; speedup vs baseline: 2.1003x; 1.0710x over previous
//
#include <hip/hip_runtime.h>

#define D_ 1024
#define S_ 2048
#define B_ 32
#define BM 128
#define BN 256
#define BK 64
#define NKT 32  // K tiles: 16 from W/k + 16 from U/q (BK=64)

typedef __attribute__((ext_vector_type(8))) _Float16 f16x8;  // 4 VGPR MFMA operand
typedef __attribute__((ext_vector_type(16))) float f32x16;   // MFMA 32x32 acc

// async global->LDS, 16B per lane. LDS dest is wave-uniform base + lane*16;
// our per-lane pointers are linear in lane, so this matches exactly.
__device__ __forceinline__ void async_ld16(const void* g, void* l) {
  __builtin_amdgcn_global_load_lds(
      (const __attribute__((address_space(1))) void*)g,
      (__attribute__((address_space(3))) void*)l, 16, 0, 0);
}

// ---------------------------------------------------------------------------
// prep: round W,U to single f16 plane, stored in FRAGMENT ORDER per 128x64
// tile (1024 granules of 8 f16) — layout identical to R5 (verified):
//   granule = ((ks*4 + wr*2 + fm) << 6) | (lhi << 5) | l31
//   row     = wr*64 + fm*32 + l31      (d within tile)
//   chunk   = ks*2 + lhi               (8-elem k-group within 64)
// ---------------------------------------------------------------------------
__global__ void prep_kernel(const float* __restrict__ W, const float* __restrict__ U,
                            _Float16* __restrict__ wf, _Float16* __restrict__ uf) {
  int t = blockIdx.x * blockDim.x + threadIdx.x;  // [0, 131072) granules
  const float* src = blockIdx.y ? U : W;
  _Float16* dst = blockIdx.y ? uf : wf;

  int tile = t >> 10;       // [0,128) = mt*16 + kt
  int g    = t & 1023;      // granule within tile
  int top  = g >> 6;        // [0,16)
  int ks = top >> 2, wr = (top >> 1) & 1, fm = top & 1;
  int lhi = (g >> 5) & 1, l31 = g & 31;
  int row   = wr * 64 + fm * 32 + l31;
  int chunk = ks * 2 + lhi;
  int mt = tile >> 4, kt = tile & 15;
  int d = mt * 128 + row;
  int e = kt * 64 + chunk * 8;

  const float* p = src + (size_t)d * D_ + e;
  f16x8 hv;
#pragma unroll
  for (int j = 0; j < 8; ++j) hv[j] = (_Float16)p[j];  // RN
  *(f16x8*)(dst + (size_t)t * 8) = hv;                 // linear, coalesced
}

// ---------------------------------------------------------------------------
// gemm v7 (v6 + OOB fix): 128x256 tile, 8 waves (2x4), BK=64, 1-pass f16.
// Pipeline per kt (T14 async-stage split + A dbuf):
//   issue A(kt+1)->A[nxt] (global_load_lds, EXACTLY 1024 granules)
//   issue B(kt+1)->regs (32 coalesced f32)            [latency hidden]
//   compute A[cur] x B from LDS (16 MFMA/wave)
//   barrier; cvt+ds_write B(kt+1); barrier (drains vmcnt)
// B single-buffered: write-after-barrier is race-free. LDS ~66.5KB -> 2 blk/CU.
// ---------------------------------------------------------------------------
__global__ void __launch_bounds__(512, 4)
gemm_kernel(const float* __restrict__ kten, const float* __restrict__ qten,
            const float* __restrict__ v,
            const _Float16* __restrict__ wf, const _Float16* __restrict__ uf,
            float* __restrict__ partials) {
  __shared__ __align__(16) _Float16 Af[2][BM * BK];  // 2 x 16 KB
  __shared__ __align__(16) _Float16 Bf[BN * BK];     // 32 KB
  __shared__ float vbuf[BM];
  __shared__ float red[2][BN];

  const int tid  = threadIdx.x;
  const int lane = tid & 63;
  const int wid  = tid >> 6;        // [0,8)
  const int wr   = wid >> 2;        // [0,2) d-half
  const int wc   = wid & 3;         // [0,4) s-quarter

  // Block decode: 2048 blocks = 256 groups x 8 dblk. The 8 d-siblings of a
  // (b, s-tile) group share bid&7 -> same XCD -> k/q tiles served from L2.
  int bid  = blockIdx.x;
  int g    = ((bid >> 6) << 3) | (bid & 7);  // [0,256)
  int dblk = (bid >> 3) & 7;
  int st   = g & 7;
  int b    = g >> 3;
  int s0   = st * BN;

  if (tid < BM) vbuf[tid] = v[(size_t)b * D_ + dblk * BM + tid];

  f32x16 acc[2][2];
#pragma unroll
  for (int i = 0; i < 2; ++i)
#pragma unroll
    for (int j = 0; j < 2; ++j)
#pragma unroll
      for (int r = 0; r < 16; ++r) acc[i][j][r] = 0.0f;

  const int nB = tid & 255;  // B-stage column within s-tile
  const int kq = tid >> 8;   // 0/1: which 32 of the 64 k-rows this thread loads

  // --- staging helpers -----------------------------------------------------
  auto issueA = [&](int kt, int buf) {
    const int half = kt >> 4, ktt = kt & 15;
    const _Float16* at = (half ? uf : wf) + (size_t)(dblk * 16 + ktt) * 8192;
    // EXACTLY 1024 granules = 16KB tile (512 threads x 2). R6's 4-iter loop
    // overran by 16KB: OOB global reads (NaN f16 patterns) + LDS clobber.
#pragma unroll
    for (int i = 0; i < 2; ++i)
      async_ld16(at + (size_t)(tid + i * 512) * 8, &Af[buf][(size_t)(tid + i * 512) * 8]);
  };
  auto loadB = [&](int kt, float* xv) {
    const int half = kt >> 4, ktt = kt & 15;
    const float* xb = (half ? qten : kten) + (size_t)b * (D_ * S_) + (size_t)(ktt * 64) * S_ + s0;
    const float* col = xb + nB + (size_t)(kq * 32) * S_;
#pragma unroll
    for (int j = 0; j < 32; ++j) xv[j] = col[(size_t)j * S_];
  };
  auto splitB = [&](const float* xv) {
#pragma unroll
    for (int cl = 0; cl < 4; ++cl) {          // chunk-local: 4 chunks of 8 rows
      f16x8 hv;
#pragma unroll
      for (int w = 0; w < 8; ++w) hv[w] = (_Float16)xv[cl * 8 + w];
      int c   = kq * 4 + cl;                  // chunk in [0,8)
      int cks = c >> 1, clh = c & 1;
      // granule = ((ks*8 + wc_n*2 + fn_n) << 6) | (lhi<<5) | l31
      int gnl = (((cks * 8 + (nB >> 6) * 2 + ((nB >> 5) & 1)) << 6) | (clh << 5) | (nB & 31));
      *(f16x8*)&Bf[(size_t)gnl * 8] = hv;
    }
  };

  // --- prologue: stage kt=0 -------------------------------------------------
  float xv[32];
  issueA(0, 0);
  loadB(0, xv);
  splitB(xv);          // compiler waits vmcnt for xv before cvt
  __syncthreads();     // drains A gll + B ds_writes

  int cur = 0;
  for (int kt = 0; kt < NKT; ++kt) {
    const int nxt = cur ^ 1;
    const bool pre = (kt + 1 < NKT);

    // ---- issue next-tile loads; latency hides under compute below ----
    if (pre) {
      issueA(kt + 1, nxt);
      loadB(kt + 1, xv);
    }

    // ---- compute current: 4 k-steps x 2x2 frags = 16 MFMA / wave ----
#pragma unroll
    for (int ks = 0; ks < 4; ++ks) {
      f16x8 af[2], bf[2];
#pragma unroll
      for (int fm = 0; fm < 2; ++fm) {
        int gA = ((ks * 4 + wr * 2 + fm) << 6) + lane;  // contiguous per wave
        af[fm] = *(const f16x8*)&Af[cur][(size_t)gA * 8];
      }
#pragma unroll
      for (int fn = 0; fn < 2; ++fn) {
        int gB = ((ks * 8 + wc * 2 + fn) << 6) + lane;
        bf[fn] = *(const f16x8*)&Bf[(size_t)gB * 8];
      }
#pragma unroll
      for (int fm = 0; fm < 2; ++fm)
#pragma unroll
        for (int fn = 0; fn < 2; ++fn)
          acc[fm][fn] = __builtin_amdgcn_mfma_f32_32x32x16_f16(af[fm], bf[fn], acc[fm][fn], 0, 0, 0);
    }

    __syncthreads();            // all waves done reading Bf (and Af[cur])
    if (pre) splitB(xv);        // cvt + write B(kt+1); waits its loads only
    __syncthreads();            // B writes + A[nxt] gll visible (vmcnt drain)
    cur = nxt;
  }

  // ---- epilogue: tanh, weight by v[d], column-reduce the 128 d-rows ----
  float psum[2] = {0.f, 0.f};
#pragma unroll
  for (int fm = 0; fm < 2; ++fm)
#pragma unroll
    for (int fn = 0; fn < 2; ++fn)
#pragma unroll
      for (int r = 0; r < 16; ++r) {
        // C/D layout: col = lane&31, row = (r&3)+8*(r>>2)+4*(lane>>5)
        int row = wr * 64 + fm * 32 + (r & 3) + 8 * (r >> 2) + 4 * (lane >> 5);
        float x  = acc[fm][fn][r];
        float th = 1.0f - 2.0f / (__expf(2.0f * x) + 1.0f);  // tanh(x)
        psum[fn] += vbuf[row] * th;
      }
#pragma unroll
  for (int fn = 0; fn < 2; ++fn) psum[fn] += __shfl_xor(psum[fn], 32);
  if (lane < 32) {
    red[wr][wc * 64 + lane]      = psum[0];
    red[wr][wc * 64 + 32 + lane] = psum[1];
  }
  __syncthreads();
  if (tid < BN) {
    float val = red[0][tid] + red[1][tid];
    partials[(size_t)(dblk * B_ + b) * S_ + s0 + tid] = val;
  }
}

// ---------------------------------------------------------------------------
// softmax over S per batch; sums the 8 d-block partials first. Deterministic.
// ---------------------------------------------------------------------------
__global__ void softmax_kernel(const float* __restrict__ partials, float* __restrict__ out) {
  __shared__ float logit[S_];
  __shared__ float wred[2][4];
  int b = blockIdx.x, tid = threadIdx.x;
  int lane = tid & 63, wid = tid >> 6;
  float lmax = -1e30f;
  for (int i = tid; i < S_; i += 256) {
    float acc = 0.f;
#pragma unroll
    for (int d = 0; d < 8; ++d) acc += partials[(size_t)(d * B_ + b) * S_ + i];
    logit[i] = acc;
    lmax = fmaxf(lmax, acc);
  }
#pragma unroll
  for (int o = 32; o; o >>= 1) lmax = fmaxf(lmax, __shfl_xor(lmax, o));
  if (lane == 0) wred[0][wid] = lmax;
  __syncthreads();
  float m = fmaxf(fmaxf(wred[0][0], wred[0][1]), fmaxf(wred[0][2], wred[0][3]));
  float lsum = 0.f;
  for (int i = tid; i < S_; i += 256) {
    float ex = __expf(logit[i] - m);
    logit[i] = ex;
    lsum += ex;
  }
#pragma unroll
  for (int o = 32; o; o >>= 1) lsum += __shfl_xor(lsum, o);
  if (lane == 0) wred[1][wid] = lsum;
  __syncthreads();
  float tot = wred[1][0] + wred[1][1] + wred[1][2] + wred[1][3];
  float inv = 1.0f / tot;
  for (int i = tid; i < S_; i += 256) out[(size_t)b * S_ + i] = logit[i] * inv;
}

extern "C" void kernel_launch(void* const* d_in, const int* in_sizes, int n_in,
                              void* d_out, int out_size, void* d_ws, size_t ws_size,
                              hipStream_t stream) {
  const float* q = (const float*)d_in[0];
  const float* k = (const float*)d_in[1];
  const float* v = (const float*)d_in[2];
  const float* W = (const float*)d_in[3];
  const float* U = (const float*)d_in[4];

  // ws layout: 2x f16[1024*1024] (4 MB) + partials f32[8][32][2048] (2 MB)
  _Float16* wf = (_Float16*)d_ws;
  _Float16* uf = wf + (size_t)D_ * D_;
  float* partials = (float*)(uf + (size_t)D_ * D_);

  prep_kernel<<<dim3(512, 2), 256, 0, stream>>>(W, U, wf, uf);
  gemm_kernel<<<dim3(2048), 512, 0, stream>>>(k, q, v, wf, uf, partials);
  softmax_kernel<<<dim3(B_), 256, 0, stream>>>(partials, (float*)d_out);
}